// Round 2
// baseline (1460.572 us; speedup 1.0000x reference)
//
#include <hip/hip_runtime.h>

#define N_CTX 4096
#define DHEAD 64
#define NBH   16
#define LDK   40   // LDS row stride for 32-wide tiles (P, V^T) — 2-way banks only
#define LDKK  72   // LDS row stride for 64-wide K tiles (64 + 8 pad)

typedef _Float16 half8 __attribute__((ext_vector_type(8)));
typedef float    f32x4 __attribute__((ext_vector_type(4)));

__global__ __launch_bounds__(256, 4)
void attn_fused(const float* __restrict__ Q, const float* __restrict__ K,
                const float* __restrict__ V, float* __restrict__ out)
{
    const int bh     = blockIdx.y;
    const int rowblk = blockIdx.x;
    const int tid  = threadIdx.x;
    const int wave = tid >> 6;
    const int lane = tid & 63;
    const int l15  = lane & 15;
    const int quad = lane >> 4;

    __shared__ __attribute__((aligned(16))) _Float16 s_k[32 * LDKK];  // [key][d]
    __shared__ __attribute__((aligned(16))) _Float16 s_v[64 * LDK];   // transposed: [d][key]
    __shared__ __attribute__((aligned(16))) _Float16 s_p[4][16 * LDK];

    const size_t base = (size_t)bh * N_CTX * DHEAD;
    const int gr0 = rowblk * 64 + wave * 16;

    // Q A-fragments: A[m=l15][k=32h+8*quad+i], scale 1/8 folded (exact in f16)
    half8 aq[2];
    {
        const float* qp = Q + base + (size_t)(gr0 + l15) * DHEAD;
        #pragma unroll
        for (int h = 0; h < 2; ++h) {
            const float4 f0 = *(const float4*)(qp + 32*h + 8*quad);
            const float4 f1 = *(const float4*)(qp + 32*h + 8*quad + 4);
            half8 a;
            a[0]=(_Float16)(f0.x*0.125f); a[1]=(_Float16)(f0.y*0.125f);
            a[2]=(_Float16)(f0.z*0.125f); a[3]=(_Float16)(f0.w*0.125f);
            a[4]=(_Float16)(f1.x*0.125f); a[5]=(_Float16)(f1.y*0.125f);
            a[6]=(_Float16)(f1.z*0.125f); a[7]=(_Float16)(f1.w*0.125f);
            aq[h] = a;
        }
    }

    const int st_key = tid >> 3, st_c  = tid & 7;  // K stage: 32 rows x 8 chunks of 8
    const int sv_d   = tid >> 2, sv_kc = tid & 3;  // V stage: 64 d-rows x 4 key-chunks of 8

    f32x4 oacc[4] = {{0.f,0.f,0.f,0.f},{0.f,0.f,0.f,0.f},
                     {0.f,0.f,0.f,0.f},{0.f,0.f,0.f,0.f}};
    float lacc[4] = {0.f, 0.f, 0.f, 0.f};

    // ---------------- pass A: row sums l and O = softmax(S) V ----------------
    for (int jt = 0; jt < N_CTX / 32; ++jt) {
        const int j0 = jt * 32;
        __syncthreads();
        {   // stage K tile [32 keys][64 d] as f16 (natural layout)
            const float* kp = K + base + (size_t)(j0 + st_key) * DHEAD + 8*st_c;
            const float4 f0 = *(const float4*)kp;
            const float4 f1 = *(const float4*)(kp + 4);
            half8 a;
            a[0]=(_Float16)f0.x; a[1]=(_Float16)f0.y; a[2]=(_Float16)f0.z; a[3]=(_Float16)f0.w;
            a[4]=(_Float16)f1.x; a[5]=(_Float16)f1.y; a[6]=(_Float16)f1.z; a[7]=(_Float16)f1.w;
            *(half8*)&s_k[st_key * LDKK + 8*st_c] = a;
        }
        {   // stage V transposed: s_v[d][key]  (gather 8 rows of one column)
            const float* vp = V + base + (size_t)(j0 + 8*sv_kc) * DHEAD + sv_d;
            half8 a;
            #pragma unroll
            for (int j = 0; j < 8; ++j) a[j] = (_Float16)vp[j * DHEAD];
            *(half8*)&s_v[sv_d * LDK + 8*sv_kc] = a;
        }
        __syncthreads();

        f32x4 sc[2];
        #pragma unroll
        for (int jj = 0; jj < 2; ++jj) {
            const half8 b0 = *(const half8*)&s_k[(16*jj + l15) * LDKK + 8*quad];
            const half8 b1 = *(const half8*)&s_k[(16*jj + l15) * LDKK + 32 + 8*quad];
            f32x4 acc = {0.f,0.f,0.f,0.f};
            acc = __builtin_amdgcn_mfma_f32_16x16x32_f16(aq[0], b0, acc, 0, 0, 0);
            acc = __builtin_amdgcn_mfma_f32_16x16x32_f16(aq[1], b1, acc, 0, 0, 0);
            sc[jj] = acc;
        }
        // p = exp(s); accumulate l per-lane; stage P for the PV A-operand
        #pragma unroll
        for (int jj = 0; jj < 2; ++jj)
            #pragma unroll
            for (int r = 0; r < 4; ++r) {
                const float p = __expf(sc[jj][r]);
                lacc[r] += p;
                s_p[wave][(4*quad + r) * LDK + 16*jj + l15] = (_Float16)p;
            }
        __syncthreads();
        const half8 ap = *(const half8*)&s_p[wave][l15 * LDK + 8*quad];
        #pragma unroll
        for (int dt = 0; dt < 4; ++dt) {
            const half8 bv = *(const half8*)&s_v[(16*dt + l15) * LDK + 8*quad];
            oacc[dt] = __builtin_amdgcn_mfma_f32_16x16x32_f16(ap, bv, oacc[dt], 0, 0, 0);
        }
    }

    // reduce l across the 16 lanes of each quad (rows 4*quad+r)
    float inv[4];
    #pragma unroll
    for (int r = 0; r < 4; ++r) {
        float s = lacc[r];
        s += __shfl_xor(s, 1); s += __shfl_xor(s, 2);
        s += __shfl_xor(s, 4); s += __shfl_xor(s, 8);
        inv[r] = 1.0f / s;
    }

    {   // store O = oacc / l ; O region is first NBH*N*D floats of out
        float* op = out + base + (size_t)gr0 * DHEAD;
        #pragma unroll
        for (int dt = 0; dt < 4; ++dt)
            #pragma unroll
            for (int r = 0; r < 4; ++r)
                op[(size_t)(4*quad + r) * DHEAD + 16*dt + l15] = oacc[dt][r] * inv[r];
    }

    // ---------------- pass B: recompute S, write attention = exp(S)/l ----------------
    float* ap_out = out + (size_t)NBH * N_CTX * DHEAD
                  + (size_t)bh * N_CTX * N_CTX + (size_t)gr0 * N_CTX;
    for (int jt = 0; jt < N_CTX / 32; ++jt) {
        const int j0 = jt * 32;
        __syncthreads();
        {   // stage K tile
            const float* kp = K + base + (size_t)(j0 + st_key) * DHEAD + 8*st_c;
            const float4 f0 = *(const float4*)kp;
            const float4 f1 = *(const float4*)(kp + 4);
            half8 a;
            a[0]=(_Float16)f0.x; a[1]=(_Float16)f0.y; a[2]=(_Float16)f0.z; a[3]=(_Float16)f0.w;
            a[4]=(_Float16)f1.x; a[5]=(_Float16)f1.y; a[6]=(_Float16)f1.z; a[7]=(_Float16)f1.w;
            *(half8*)&s_k[st_key * LDKK + 8*st_c] = a;
        }
        __syncthreads();
        #pragma unroll
        for (int jj = 0; jj < 2; ++jj) {
            const half8 b0 = *(const half8*)&s_k[(16*jj + l15) * LDKK + 8*quad];
            const half8 b1 = *(const half8*)&s_k[(16*jj + l15) * LDKK + 32 + 8*quad];
            f32x4 acc = {0.f,0.f,0.f,0.f};
            acc = __builtin_amdgcn_mfma_f32_16x16x32_f16(aq[0], b0, acc, 0, 0, 0);
            acc = __builtin_amdgcn_mfma_f32_16x16x32_f16(aq[1], b1, acc, 0, 0, 0);
            #pragma unroll
            for (int r = 0; r < 4; ++r)
                ap_out[(size_t)(4*quad + r) * N_CTX + j0 + 16*jj + l15]
                    = __expf(acc[r]) * inv[r];
        }
    }
}

extern "C" void kernel_launch(void* const* d_in, const int* in_sizes, int n_in,
                              void* d_out, int out_size, void* d_ws, size_t ws_size,
                              hipStream_t stream)
{
    const float* q = (const float*)d_in[0];
    const float* k = (const float*)d_in[1];
    const float* v = (const float*)d_in[2];
    float* o = (float*)d_out;
    dim3 grid(N_CTX / 64, NBH), block(256);
    hipLaunchKernelGGL(attn_fused, grid, block, 0, stream, q, k, v, o);
}